// Round 8
// baseline (136.728 us; speedup 1.0000x reference)
//
#include <hip/hip_runtime.h>
#include <hip/hip_bf16.h>

#define NN 20000
#define NE 640000
#define F  128
#define MAXDEG 96   // slots per node; deg ~ Poisson(32), 96 is ~11 sigma out

typedef __attribute__((ext_vector_type(8))) short s16x8;
typedef __attribute__((ext_vector_type(4))) short s16x4;

__device__ __forceinline__ float bf16_to_f32(short x) {
    union { unsigned u; float f; } c;
    c.u = ((unsigned)(unsigned short)x) << 16;
    return c.f;
}
__device__ __forceinline__ unsigned short f32_to_bf16u(float f) {
    __hip_bfloat16 b = __float2bfloat16(f);
    return *reinterpret_cast<unsigned short*>(&b);
}

// direct-slot CSR: slot = atomicAdd(cnt[d]), eid[d*MAXDEG+slot] = e
__global__ __launch_bounds__(256) void k_fill(const int* __restrict__ dst,
                                              int* __restrict__ cnt,
                                              int* __restrict__ eid) {
    int t = blockIdx.x * 256 + threadIdx.x;
    if (t * 4 >= NE) return;
    int4 d = reinterpret_cast<const int4*>(dst)[t];
    int e0 = t * 4;
    eid[d.x * MAXDEG + atomicAdd(&cnt[d.x], 1)] = e0;
    eid[d.y * MAXDEG + atomicAdd(&cnt[d.y], 1)] = e0 + 1;
    eid[d.z * MAXDEG + atomicAdd(&cnt[d.z], 1)] = e0 + 2;
    eid[d.w * MAXDEG + atomicAdd(&cnt[d.w], 1)] = e0 + 3;
}

// one wave per node; paired rows: lanes 0-31 edge a, lanes 32-63 edge b,
// float4/lane = 1KB/instr, 4 pairs (8 rows, 4KB) in flight.
__global__ __launch_bounds__(256) void k_gather(const float* __restrict__ ef,
                                                const int* __restrict__ eid,
                                                const int* __restrict__ cnt,
                                                __hip_bfloat16* __restrict__ h) {
    int wid = (blockIdx.x * 256 + threadIdx.x) >> 6;  // node id
    int lane = threadIdx.x & 63;
    if (wid >= NN) return;
    const int deg = cnt[wid];
    const int* list = eid + wid * MAXDEG;
    int half = lane >> 5;
    int q = lane & 31;
    const float* basep = ef + q * 4;
    float ax = 0.0f, ay = 0.0f, az = 0.0f, aw = 0.0f;
    int i = 0;
    for (; i + 7 < deg; i += 8) {
        int e0 = list[i + half];
        int e1 = list[i + 2 + half];
        int e2 = list[i + 4 + half];
        int e3 = list[i + 6 + half];
        float4 v0 = *reinterpret_cast<const float4*>(basep + (size_t)e0 * F);
        float4 v1 = *reinterpret_cast<const float4*>(basep + (size_t)e1 * F);
        float4 v2 = *reinterpret_cast<const float4*>(basep + (size_t)e2 * F);
        float4 v3 = *reinterpret_cast<const float4*>(basep + (size_t)e3 * F);
        ax += (v0.x + v1.x) + (v2.x + v3.x);
        ay += (v0.y + v1.y) + (v2.y + v3.y);
        az += (v0.z + v1.z) + (v2.z + v3.z);
        aw += (v0.w + v1.w) + (v2.w + v3.w);
    }
    for (; i + 1 < deg; i += 2) {
        int e0 = list[i + half];
        float4 v0 = *reinterpret_cast<const float4*>(basep + (size_t)e0 * F);
        ax += v0.x; ay += v0.y; az += v0.z; aw += v0.w;
    }
    if (i < deg && half == 0) {
        int e0 = list[i];
        float4 v0 = *reinterpret_cast<const float4*>(basep + (size_t)e0 * F);
        ax += v0.x; ay += v0.y; az += v0.z; aw += v0.w;
    }
    ax += __shfl_xor(ax, 32);
    ay += __shfl_xor(ay, 32);
    az += __shfl_xor(az, 32);
    aw += __shfl_xor(aw, 32);
    if (half == 0) {
        ushort4 r;
        r.x = f32_to_bf16u(ax);
        r.y = f32_to_bf16u(ay);
        r.z = f32_to_bf16u(az);
        r.w = f32_to_bf16u(aw);
        reinterpret_cast<ushort4*>(h)[(size_t)wid * 32 + q] = r;
    }
}

// GEMM: out[n][o] = (sum_k h[n][k]*W[o][k] + b[o]) * rsqrt(max(deg[n],1))
#define TM 64
#define WT_LD 136
#define HT_LD 72

__global__ __launch_bounds__(256) void k_gemm(
        const __hip_bfloat16* __restrict__ h, const float* __restrict__ W,
        const float* __restrict__ bias, const int* __restrict__ cnt,
        float* __restrict__ out) {
    __shared__ __hip_bfloat16 Wt[128 * WT_LD];
    __shared__ __hip_bfloat16 hT[128 * HT_LD];
    const int t = threadIdx.x;
    const int base = blockIdx.x * TM;

    for (int e = t; e < F * F; e += 256) {
        int o = e >> 7, i = e & 127;
        Wt[i * WT_LD + o] = __float2bfloat16(W[e]);
    }
    for (int e4 = t; e4 < TM * (F / 4); e4 += 256) {
        int n = e4 >> 5, k4 = e4 & 31;
        int gn = base + n;
        ushort4 v;
        if (gn < NN) v = *reinterpret_cast<const ushort4*>(h + (size_t)gn * F + k4 * 4);
        else v = ushort4{0, 0, 0, 0};
        int k = k4 * 4;
        hT[(k + 0) * HT_LD + n] = *reinterpret_cast<__hip_bfloat16*>(&v.x);
        hT[(k + 1) * HT_LD + n] = *reinterpret_cast<__hip_bfloat16*>(&v.y);
        hT[(k + 2) * HT_LD + n] = *reinterpret_cast<__hip_bfloat16*>(&v.z);
        hT[(k + 3) * HT_LD + n] = *reinterpret_cast<__hip_bfloat16*>(&v.w);
    }
    __syncthreads();

    const int tx = t & 31, ty = t >> 5;
    const int o0 = tx * 4, n0 = ty * 8;

    float acc[8][4];
    #pragma unroll
    for (int i = 0; i < 8; ++i)
        #pragma unroll
        for (int j = 0; j < 4; ++j) acc[i][j] = 0.0f;

    #pragma unroll 4
    for (int k = 0; k < F; ++k) {
        s16x8 hv = *reinterpret_cast<const s16x8*>(&hT[k * HT_LD + n0]);
        s16x4 wv = *reinterpret_cast<const s16x4*>(&Wt[k * WT_LD + o0]);
        float wf[4], hf[8];
        #pragma unroll
        for (int j = 0; j < 4; ++j) wf[j] = bf16_to_f32(wv[j]);
        #pragma unroll
        for (int i = 0; i < 8; ++i) hf[i] = bf16_to_f32(hv[i]);
        #pragma unroll
        for (int i = 0; i < 8; ++i)
            #pragma unroll
            for (int j = 0; j < 4; ++j)
                acc[i][j] = fmaf(hf[i], wf[j], acc[i][j]);
    }

    const float4 bv = *reinterpret_cast<const float4*>(&bias[o0]);
    #pragma unroll
    for (int i = 0; i < 8; ++i) {
        int gn = base + n0 + i;
        if (gn >= NN) break;
        float deg = (float)cnt[gn];
        float s = rsqrtf(fmaxf(deg, 1.0f));
        float4 r;
        r.x = (acc[i][0] + bv.x) * s;
        r.y = (acc[i][1] + bv.y) * s;
        r.z = (acc[i][2] + bv.z) * s;
        r.w = (acc[i][3] + bv.w) * s;
        *reinterpret_cast<float4*>(&out[(size_t)gn * F + o0]) = r;
    }
}

extern "C" void kernel_launch(void* const* d_in, const int* in_sizes, int n_in,
                              void* d_out, int out_size, void* d_ws, size_t ws_size,
                              hipStream_t stream) {
    // inputs: 0 node_feats (unused), 1 edge_feats, 2 W, 3 b, 4 src (unused), 5 dst
    const float* edge_feats = (const float*)d_in[1];
    const float* W          = (const float*)d_in[2];
    const float* bias       = (const float*)d_in[3];
    const int*   dst        = (const int*)d_in[5];
    float* out = (float*)d_out;

    // workspace: eid[NN*MAXDEG] | cnt[NN] | h_bf16[NN*F]
    int* eid = (int*)d_ws;
    int* cnt = eid + (size_t)NN * MAXDEG;
    __hip_bfloat16* h = (__hip_bfloat16*)(cnt + NN);   // even offset -> 8B aligned

    hipMemsetAsync(cnt, 0, NN * sizeof(int), stream);
    k_fill<<<(NE / 4 + 255) / 256, 256, 0, stream>>>(dst, cnt, eid);
    k_gather<<<(NN * 64 + 255) / 256, 256, 0, stream>>>(edge_feats, eid, cnt, h);
    k_gemm<<<(NN + TM - 1) / TM, 256, 0, stream>>>(h, W, bias, cnt, out);
}